// Round 1
// baseline (217.597 us; speedup 1.0000x reference)
//
#include <hip/hip_runtime.h>

// Problem constants (match reference setup_inputs)
constexpr int Bb = 64;
constexpr int T  = 4096;
constexpr int D  = 256;
constexpr int A  = 10;
// per-row outputs: cls = A*C = 20, bbox = A*2 = 20, proposals = A*2 = 20
// output layout (floats): anchors [T*A*2] | proposals [B*T*A*2] | cls [B*T*A*2] | bbox [B*T*A*2]
constexpr size_t ANCHORS_N = (size_t)T * A * 2;          // 81920
constexpr size_t PER_TENSOR = (size_t)Bb * T * A * 2;    // 5242880

__global__ void anchors_k(float* __restrict__ out) {
    int i = blockIdx.x * 256 + threadIdx.x;   // over T*A
    if (i >= T * A) return;
    int t = i / A;
    int a = i - t * A;
    float L = fmaf((float)a, 160.0f / 9.0f, 40.0f);  // linspace(40,200,10)
    float h = 0.5f * (L - 1.0f);
    reinterpret_cast<float2*>(out)[i] = make_float2((float)t - h, (float)t + h);
}

__global__ __launch_bounds__(256) void rpn_k(
    const float* __restrict__ x,
    const float* __restrict__ Wc, const float* __restrict__ bc,
    const float* __restrict__ Wb, const float* __restrict__ bb,
    float* __restrict__ out_prop, float* __restrict__ out_cls,
    float* __restrict__ out_bbox)
{
    const int row = blockIdx.x * 256 + threadIdx.x;   // b*T + t, exact grid
    const float* __restrict__ xr = x + (size_t)row * D;

    float accc[20];
    float accb[20];
#pragma unroll
    for (int o = 0; o < 20; ++o) { accc[o] = bc[o]; accb[o] = bb[o]; }

    for (int d0 = 0; d0 < D; d0 += 4) {
        const float4 xv = *reinterpret_cast<const float4*>(xr + d0);
#pragma unroll
        for (int o = 0; o < 20; ++o) {
            // uniform address across lanes -> scalar loads (K$), SGPR operands
            const float4 wc = *reinterpret_cast<const float4*>(Wc + o * D + d0);
            accc[o] = fmaf(xv.w, wc.w, fmaf(xv.z, wc.z,
                      fmaf(xv.y, wc.y, fmaf(xv.x, wc.x, accc[o]))));
        }
#pragma unroll
        for (int o = 0; o < 20; ++o) {
            const float4 wb = *reinterpret_cast<const float4*>(Wb + o * D + d0);
            accb[o] = fmaf(xv.w, wb.w, fmaf(xv.z, wb.z,
                      fmaf(xv.y, wb.y, fmaf(xv.x, wb.x, accb[o]))));
        }
    }

    const int t = row & (T - 1);
    const size_t base = (size_t)row * 20;   // == b*(T*A*2) + t*(A*2), 16B aligned

#pragma unroll
    for (int i = 0; i < 5; ++i) {
        reinterpret_cast<float4*>(out_cls + base)[i] =
            make_float4(accc[4*i], accc[4*i+1], accc[4*i+2], accc[4*i+3]);
    }
#pragma unroll
    for (int i = 0; i < 5; ++i) {
        reinterpret_cast<float4*>(out_bbox + base)[i] =
            make_float4(accb[4*i], accb[4*i+1], accb[4*i+2], accb[4*i+3]);
    }

    // proposal decode: anchor (t,a) has center t, length L_a
    float prop[20];
#pragma unroll
    for (int a = 0; a < A; ++a) {
        const float L  = fmaf((float)a, 160.0f / 9.0f, 40.0f);
        const float dx = accb[2*a];
        const float dl = accb[2*a + 1];
        const float ctr = fmaf(dx, L, (float)t);
        const float pl  = __expf(dl) * L;
        const float h   = 0.5f * (pl - 1.0f);
        float s = ctr - h;
        float e = ctr + h;
        s = fminf(fmaxf(s, 0.0f), (float)(T - 1));
        e = fminf(fmaxf(e, 0.0f), (float)(T - 1));
        prop[2*a]     = s;
        prop[2*a + 1] = e;
    }
#pragma unroll
    for (int i = 0; i < 5; ++i) {
        reinterpret_cast<float4*>(out_prop + base)[i] =
            make_float4(prop[4*i], prop[4*i+1], prop[4*i+2], prop[4*i+3]);
    }
}

extern "C" void kernel_launch(void* const* d_in, const int* in_sizes, int n_in,
                              void* d_out, int out_size, void* d_ws, size_t ws_size,
                              hipStream_t stream) {
    const float* x  = (const float*)d_in[0];
    const float* Wc = (const float*)d_in[1];
    const float* bc = (const float*)d_in[2];
    const float* Wb = (const float*)d_in[3];
    const float* bb = (const float*)d_in[4];

    float* out      = (float*)d_out;
    float* anchors  = out;
    float* prop     = out + ANCHORS_N;
    float* cls      = out + ANCHORS_N + PER_TENSOR;
    float* bbox     = out + ANCHORS_N + 2 * PER_TENSOR;

    anchors_k<<<(T * A + 255) / 256, 256, 0, stream>>>(anchors);

    const int rows = Bb * T;                 // 262144
    rpn_k<<<rows / 256, 256, 0, stream>>>(x, Wc, bc, Wb, bb, prop, cls, bbox);
}